// Round 14
// baseline (1582.655 us; speedup 1.0000x reference)
//
#include <hip/hip_runtime.h>

// LSTMNet: 2-layer LSTM (in=1, hid=32) + linear(32->1), B=2048, T=1024, fp32.
// R14: GATE-SPLIT 2-wave design with v_pk_fma_f32 (2 exact fp32 MACs/instr).
// Session law (R1-R13): the RA hard-caps this kernel at 128 VGPRs; R13's
// full-row fp32 (192 weight regs) spilled to scratch (hbm_bytes 3x). Fix:
// split each batch row across TWO waves. Wave q owns units q*16..q*16+15,
// all 4 gates: lane = g*16 + u16 -> ONE gate row per lane ->
//   Whh0[R]+Wih1[R]+Whh1[R] = 48 f2 = 96 VGPRs fp32 weights (fits!).
// Per wave-step: 48 pk_fma (vs 96 2-instr dot-pairs), 1 act/lane/layer,
// cell gather via 4 pre-addressed ds_bpermute (i,f,g,o all in-wave).
// 2048 blocks x 128 thr = 4096 waves = 4/SIMD. Two symmetric barriers/step
// (unlike R11's asymmetric layer split that lost to barrier skew).
// h state: h0 in a 2-slot LDS ring; h1 in a 64-slot store that doubles as
// the chunk-hoisted head input (R7 technique).

typedef float f2 __attribute__((ext_vector_type(2)));
typedef float f4 __attribute__((ext_vector_type(4)));

constexpr int BATCH = 2048;
constexpr int TLEN  = 1024;
constexpr int HID   = 32;
constexpr float L2E = 1.44269504088896f;   // log2(e)

union F4U { f4 v; f2 p[2]; };

static __device__ __forceinline__ float rcp_f(float v){ return __builtin_amdgcn_rcpf(v); }
static __device__ __forceinline__ float exp2_f(float v){ return __builtin_amdgcn_exp2f(v); }
static __device__ __forceinline__ float bcastf(float v, int k){
    return __int_as_float(__builtin_amdgcn_readlane(__float_as_int(v), k));
}
static __device__ __forceinline__ f2 fma2(f2 a, f2 b, f2 c){
    return __builtin_elementwise_fma(a, b, c);   // -> v_pk_fma_f32
}
static __device__ __forceinline__ float bperm(int addr, float v){
    return __int_as_float(__builtin_amdgcn_ds_bpermute(addr, __float_as_int(v)));
}

__global__ void __launch_bounds__(128)
lstm2_v14(const float* __restrict__ x,
          const float* __restrict__ Wih0, const float* __restrict__ Whh0,
          const float* __restrict__ bih0, const float* __restrict__ bhh0,
          const float* __restrict__ Wih1, const float* __restrict__ Whh1,
          const float* __restrict__ bih1, const float* __restrict__ bhh1,
          const float* __restrict__ Wlin, const float* __restrict__ blin,
          float* __restrict__ out)
{
    const int tid = threadIdx.x;
    const int l   = tid & 63;
    const int q   = tid >> 6;                // wave: which 16-unit half
    const int b   = blockIdx.x;              // batch row (one per block)
    const int g   = l >> 4;                  // gate 0=i 1=f 2=g 3=o
    const int u   = q * 16 + (l & 15);       // hidden unit 0..31
    const int R   = 32 * g + u;              // gate row in the weight matrices

    __shared__ alignas(16) float h0r[2][32];     // h0 2-slot ring
    __shared__ alignas(16) float h1s[64][36];    // h1 per step (recurrence + head)
    __shared__ alignas(16) float wlb[32];        // Wlin copy

    if (g == 0){                             // 16 lanes/wave cover all 32 units
        h0r[0][u] = 0.0f; h0r[1][u] = 0.0f;
        h1s[63][u] = 0.0f;                   // h1_prev for t=0
        wlb[u] = Wlin[u];
    }

    // ---- per-lane weights: ONE gate row of each matrix, fp32 pairs ----
    f2 w0[16], wi[16], wh[16];               // 96 VGPRs
    #pragma unroll
    for (int m = 0; m < 16; ++m){
        w0[m] = *(const f2*)&Whh0[R * HID + 2*m];
        wi[m] = *(const f2*)&Wih1[R * HID + 2*m];
        wh[m] = *(const f2*)&Whh1[R * HID + 2*m];
    }
    const float wx = Wih0[R];
    const float b0 = bih0[R] + bhh0[R];
    const float b1 = bih1[R] + bhh1[R];
    const float bl = blin[0];

    // activation selector: g==2 (cell gate) -> tanh, else sigmoid
    const bool  isT = (g == 2);
    const float kA = isT ? (-2.0f * L2E) : (-L2E);
    const float mA = isT ?  2.0f : 1.0f;
    const float cA = isT ? -1.0f : 0.0f;

    // bpermute source addresses: gate rows i,f,g,o of MY unit (in-wave lanes)
    const int a_i = (l & 15) << 2;
    const int a_f = a_i + 64;
    const int a_g = a_i + 128;
    const int a_o = a_i + 192;

    float c0 = 0.0f, c1 = 0.0f;

    const float* xrow = x   + (size_t)b * TLEN;
    float*       orow = out + (size_t)b * TLEN;

    __syncthreads();                         // publish LDS init

    for (int tc = 0; tc < TLEN / 64; ++tc){
        const float xchunk = xrow[tc * 64 + l];      // both waves: same 64 x's

        for (int tt = 0; tt < 64; ++tt){
            const float xt = bcastf(xchunk, tt);

            // ===== layer 0: gate R = Whh0[R].h0_prev + wx*xt + b0 =====
            f2 aA  = {__builtin_fmaf(wx, xt, b0), 0.0f};
            f2 aA2 = {0.0f, 0.0f};
            {
                const f4* hv = (const f4*)&h0r[(tt + 1) & 1][0];  // h0(t-1)
                #pragma unroll
                for (int r = 0; r < 8; ++r){
                    F4U hh; hh.v = hv[r];            // broadcast read
                    aA  = fma2(w0[2*r],   hh.p[0], aA );
                    aA2 = fma2(w0[2*r+1], hh.p[1], aA2);
                }
            }
            const float g0v = (aA.x + aA.y) + (aA2.x + aA2.y);
            const float av0 = __builtin_fmaf(mA, rcp_f(1.0f + exp2_f(g0v * kA)), cA);
            // gather i,f,g,o of my unit (all in THIS wave)
            const float iv0 = bperm(a_i, av0);
            const float fv0 = bperm(a_f, av0);
            const float gv0 = bperm(a_g, av0);
            const float ov0 = bperm(a_o, av0);
            c0 = __builtin_fmaf(fv0, c0, iv0 * gv0);
            const float t0 = __builtin_fmaf(2.0f,
                    rcp_f(1.0f + exp2_f(c0 * (-2.0f * L2E))), -1.0f);
            const float h0n = ov0 * t0;
            if (g == 0) h0r[tt & 1][u] = h0n;        // publish my 16 units
            __syncthreads();                          // h0(t) visible to partner

            // ===== layer 1: gate R = Wih1[R].h0_new + Whh1[R].h1_prev + b1 =====
            f2 pA  = {b1, 0.0f};
            f2 pA2 = {0.0f, 0.0f};
            {
                const f4* hv = (const f4*)&h0r[tt & 1][0];        // h0(t)
                #pragma unroll
                for (int r = 0; r < 8; ++r){
                    F4U hh; hh.v = hv[r];
                    pA  = fma2(wi[2*r],   hh.p[0], pA );
                    pA2 = fma2(wi[2*r+1], hh.p[1], pA2);
                }
                const f4* hv1 = (const f4*)&h1s[(tt + 63) & 63][0];  // h1(t-1)
                #pragma unroll
                for (int r = 0; r < 8; ++r){
                    F4U hh; hh.v = hv1[r];
                    pA  = fma2(wh[2*r],   hh.p[0], pA );
                    pA2 = fma2(wh[2*r+1], hh.p[1], pA2);
                }
            }
            const float g1v = (pA.x + pA.y) + (pA2.x + pA2.y);
            const float av1 = __builtin_fmaf(mA, rcp_f(1.0f + exp2_f(g1v * kA)), cA);
            const float iv1 = bperm(a_i, av1);
            const float fv1 = bperm(a_f, av1);
            const float gv1 = bperm(a_g, av1);
            const float ov1 = bperm(a_o, av1);
            c1 = __builtin_fmaf(fv1, c1, iv1 * gv1);
            const float t1 = __builtin_fmaf(2.0f,
                    rcp_f(1.0f + exp2_f(c1 * (-2.0f * L2E))), -1.0f);
            const float h1n = ov1 * t1;
            if (g == 0) h1s[tt][u] = h1n;            // recurrence + head slot
            __syncthreads();                          // h1(t) visible
        }

        // ===== head for the chunk (wave 0 only): lane t' -> y[t'] =====
        if (q == 0){
            const f4* hv = (const f4*)&h1s[l][0];    // my step's h1 (32 floats)
            const f4* wv = (const f4*)&wlb[0];
            f2 y  = {bl, 0.0f};
            f2 y2 = {0.0f, 0.0f};
            #pragma unroll
            for (int r = 0; r < 8; ++r){
                F4U hh; hh.v = hv[r];
                F4U ww; ww.v = wv[r];
                y  = fma2(ww.p[0], hh.p[0], y );
                y2 = fma2(ww.p[1], hh.p[1], y2);
            }
            orow[tc * 64 + l] = (y.x + y.y) + (y2.x + y2.y);   // coalesced
        }
    }
}

extern "C" void kernel_launch(void* const* d_in, const int* in_sizes, int n_in,
                              void* d_out, int out_size, void* d_ws, size_t ws_size,
                              hipStream_t stream) {
    const float* x    = (const float*)d_in[0];
    const float* Wih0 = (const float*)d_in[1];
    const float* Whh0 = (const float*)d_in[2];
    const float* bih0 = (const float*)d_in[3];
    const float* bhh0 = (const float*)d_in[4];
    const float* Wih1 = (const float*)d_in[5];
    const float* Whh1 = (const float*)d_in[6];
    const float* bih1 = (const float*)d_in[7];
    const float* bhh1 = (const float*)d_in[8];
    const float* Wlin = (const float*)d_in[9];
    const float* blin = (const float*)d_in[10];
    float* outp = (float*)d_out;

    dim3 block(128);                 // 2 waves = one batch row, gate-split
    dim3 grid(BATCH);                // 2048 blocks -> 4096 waves -> 4/SIMD
    hipLaunchKernelGGL(lstm2_v14, grid, block, 0, stream,
                       x, Wih0, Whh0, bih0, bhh0, Wih1, Whh1, bih1, bhh1,
                       Wlin, blin, outp);
}

// Round 15
// 705.443 us; speedup vs baseline: 2.2435x; 2.2435x over previous
//
#include <hip/hip_runtime.h>

// LSTMNet: 2-layer LSTM (in=1, hid=32) + linear(32->1), B=2048, T=1024, fp32.
// R15 = R12 (best: 792us, VALUBusy 82%) + software-pipelined h0 round trip.
// Session laws (R1-R14): <=128 VGPRs (R13 spill), no per-step barriers
// (R11/R14 regressions), fdot2 lowers to 2x v_fma_mix (R12 A/B) -> ~192
// 1-MAC instrs/step is the matvec floor for a self-contained wave.
// R12's one visible stall: hp0 is read back IMMEDIATELY after the h0 LDS
// write (~120cyc exposed, half-hidden at 2 waves/SIMD). Fix: issue the
// q-dots (Whh1 x h1_prev -- independent of h0) between the write and the
// read; the p-dots (Wih1 x h0_new) follow the read. Same instructions,
// same registers, reordered for the scheduler.
// One wave per batch row; 64 lanes = 32 units x 2 halves (i,f | g,o).

typedef int i4 __attribute__((ext_vector_type(4)));

constexpr int BATCH = 2048;
constexpr int TLEN  = 1024;
constexpr int HID   = 32;
constexpr float L2E = 1.44269504088896f;   // log2(e)

#if __has_builtin(__builtin_amdgcn_fdot2_f32_bf16)
typedef __bf16 e2v __attribute__((ext_vector_type(2)));
static __device__ __forceinline__ float dot2i(int a, int b, float c){
    return __builtin_amdgcn_fdot2_f32_bf16(__builtin_bit_cast(e2v, a),
                                           __builtin_bit_cast(e2v, b), c, false);
}
static __device__ __forceinline__ unsigned cvt1(float f){   // RNE to bf16 bits
    unsigned u = __float_as_uint(f);
    return (u + 0x7FFFu + ((u >> 16) & 1u)) >> 16;
}
#else
typedef _Float16 e2v __attribute__((ext_vector_type(2)));
static __device__ __forceinline__ float dot2i(int a, int b, float c){
    return __builtin_amdgcn_fdot2(__builtin_bit_cast(e2v, a),
                                  __builtin_bit_cast(e2v, b), c, false);
}
static __device__ __forceinline__ unsigned cvt1(float f){   // f16 bits
    return (unsigned)__builtin_bit_cast(unsigned short, (_Float16)f);
}
#endif

static __device__ __forceinline__ int pk2(float a, float b){
    return (int)(cvt1(a) | (cvt1(b) << 16));   // low half = a, high half = b
}

union HP { i4 v; int q[4]; };

static __device__ __forceinline__ float rcp_f(float v){ return __builtin_amdgcn_rcpf(v); }
static __device__ __forceinline__ float exp2_f(float v){ return __builtin_amdgcn_exp2f(v); }
static __device__ __forceinline__ float bcastf(float v, int k){
    return __int_as_float(__builtin_amdgcn_readlane(__float_as_int(v), k));
}
static __device__ __forceinline__ float xchg32(float v, int xaddr){
    return __int_as_float(__builtin_amdgcn_ds_bpermute(xaddr, __float_as_int(v)));
}

__global__ void __launch_bounds__(256) __attribute__((amdgpu_waves_per_eu(2, 2)))
lstm2_v15(const float* __restrict__ x,
          const float* __restrict__ Wih0, const float* __restrict__ Whh0,
          const float* __restrict__ bih0, const float* __restrict__ bhh0,
          const float* __restrict__ Wih1, const float* __restrict__ Whh1,
          const float* __restrict__ bih1, const float* __restrict__ bhh1,
          const float* __restrict__ Wlin, const float* __restrict__ blin,
          float* __restrict__ out)
{
    const int tid  = threadIdx.x;
    const int lane = tid & 63;
    const int w    = tid >> 6;                 // wave within block (0..3)
    const int b    = blockIdx.x * 4 + w;       // batch row
    const int j    = lane & 31;
    const int hi   = lane >> 5;                // 0: i,f rows   1: g,o rows
    const int rowA = hi * 64 + j;              // i (hi=0) / g (hi=1)
    const int rowB = rowA + 32;                // f (hi=0) / o (hi=1)
    const int xaddr = (lane ^ 32) << 2;        // bpermute byte addr

    __shared__ alignas(16) unsigned short hb0s[4][32];        // h0 transpose buffer
    __shared__ alignas(16) unsigned short hstore[4][64][40];  // h1 per step, 80B stride
    __shared__ alignas(16) unsigned short wls[4][32];         // packed Wlin copy

    unsigned short* hb0p = &hb0s[w][0];

    // wave-local LDS init (both halves write identical values; no barriers)
    wls[w][j] = (unsigned short)cvt1(Wlin[j]);

    // ---- per-lane weights, packed pairs, PINNED in VGPRs ----
    int wA0i[16], wB0i[16], iA1i[16], iB1i[16], hA1i[16], hB1i[16];
    #pragma unroll
    for (int m = 0; m < 16; ++m){
        wA0i[m] = pk2(Whh0[rowA * HID + 2*m], Whh0[rowA * HID + 2*m + 1]);
        wB0i[m] = pk2(Whh0[rowB * HID + 2*m], Whh0[rowB * HID + 2*m + 1]);
        iA1i[m] = pk2(Wih1[rowA * HID + 2*m], Wih1[rowA * HID + 2*m + 1]);
        iB1i[m] = pk2(Wih1[rowB * HID + 2*m], Wih1[rowB * HID + 2*m + 1]);
        hA1i[m] = pk2(Whh1[rowA * HID + 2*m], Whh1[rowA * HID + 2*m + 1]);
        hB1i[m] = pk2(Whh1[rowB * HID + 2*m], Whh1[rowB * HID + 2*m + 1]);
    }
    #pragma unroll
    for (int m = 0; m < 16; ++m){
        asm volatile("" : "+v"(wA0i[m]), "+v"(wB0i[m]), "+v"(iA1i[m]),
                          "+v"(iB1i[m]), "+v"(hA1i[m]), "+v"(hB1i[m]));
    }

    float wa0 = Wih0[rowA];
    float wb0 = Wih0[rowB];
    float ba0 = bih0[rowA] + bhh0[rowA];
    float bb0 = bih0[rowB] + bhh0[rowB];
    float ba1 = bih1[rowA] + bhh1[rowA];
    float bb1 = bih1[rowB] + bhh1[rowB];
    float bl  = blin[0];
    asm volatile("" : "+v"(wa0), "+v"(wb0), "+v"(ba0), "+v"(bb0),
                      "+v"(ba1), "+v"(bb1), "+v"(bl));

    // act-"a" selector: half0 -> sigmoid, half1 -> tanh (=2*sigm(2x)-1)
    const float kA = hi ? (-2.0f * L2E) : (-L2E);
    const float mA = hi ?  2.0f : 1.0f;
    const float cA = hi ? -1.0f : 0.0f;

    float c0 = 0.0f, c1 = 0.0f;
    HP hp0[4], hp1[4];                         // h0/h1 as packed pairs (regs)
    #pragma unroll
    for (int m = 0; m < 4; ++m){
        hp0[m].v = (i4){0,0,0,0};
        hp1[m].v = (i4){0,0,0,0};
    }

    const float* xrow = x   + (size_t)b * TLEN;
    float*       orow = out + (size_t)b * TLEN;

    for (int tc = 0; tc < TLEN / 64; ++tc){
        const float xchunk = xrow[tc * 64 + lane];   // coalesced, 64 steps

        for (int tt = 0; tt < 64; ++tt){
            const float xt = bcastf(xchunk, tt);

            // ========= layer 0: g = Whh0*h0_prev + Wih0*x + b =========
            float ga  = __builtin_fmaf(wa0, xt, ba0);
            float gb  = __builtin_fmaf(wb0, xt, bb0);
            float ga2 = 0.0f, gb2 = 0.0f;
            #pragma unroll
            for (int m = 0; m < 4; ++m){
                ga  = dot2i(wA0i[4*m+0], hp0[m].q[0], ga );
                gb  = dot2i(wB0i[4*m+0], hp0[m].q[0], gb );
                ga2 = dot2i(wA0i[4*m+1], hp0[m].q[1], ga2);
                gb2 = dot2i(wB0i[4*m+1], hp0[m].q[1], gb2);
                ga  = dot2i(wA0i[4*m+2], hp0[m].q[2], ga );
                gb  = dot2i(wB0i[4*m+2], hp0[m].q[2], gb );
                ga2 = dot2i(wA0i[4*m+3], hp0[m].q[3], ga2);
                gb2 = dot2i(wB0i[4*m+3], hp0[m].q[3], gb2);
            }
            ga += ga2; gb += gb2;

            float act_a = __builtin_fmaf(mA, rcp_f(1.0f + exp2_f(ga * kA)), cA);
            float act_b = rcp_f(1.0f + exp2_f(gb * (-L2E)));
            const float oa = xchg32(act_a, xaddr);
            const float ob = xchg32(act_b, xaddr);
            {
                const float fsel = hi ? ob : act_b;
                const float osel = hi ? act_b : ob;
                c0 = __builtin_fmaf(fsel, c0, act_a * oa);
                const float t0 = __builtin_fmaf(2.0f,
                        rcp_f(1.0f + exp2_f(c0 * (-2.0f * L2E))), -1.0f);
                const float h0 = osel * t0;
                hb0p[j] = (unsigned short)cvt1(h0);  // ds_write_b16 (both halves same)
            }

            // ========= layer 1 part A: q = Whh1*h1_prev (h0-independent) ====
            // Issued BETWEEN the h0 write and read: covers the LDS round trip.
            float qa = 0.0f, qb = 0.0f, qa2 = 0.0f, qb2 = 0.0f;
            #pragma unroll
            for (int m = 0; m < 4; ++m){
                qa  = dot2i(hA1i[4*m+0], hp1[m].q[0], qa );
                qb  = dot2i(hB1i[4*m+0], hp1[m].q[0], qb );
                qa2 = dot2i(hA1i[4*m+1], hp1[m].q[1], qa2);
                qb2 = dot2i(hB1i[4*m+1], hp1[m].q[1], qb2);
                qa  = dot2i(hA1i[4*m+2], hp1[m].q[2], qa );
                qb  = dot2i(hB1i[4*m+2], hp1[m].q[2], qb );
                qa2 = dot2i(hA1i[4*m+3], hp1[m].q[3], qa2);
                qb2 = dot2i(hB1i[4*m+3], hp1[m].q[3], qb2);
            }

            // now read h0_new back (latency covered by the q-dots above)
            {
                const i4* hv = (const i4*)hb0p;
                #pragma unroll
                for (int m = 0; m < 4; ++m) hp0[m].v = hv[m];
            }

            // ========= layer 1 part B: p = Wih1*h0_new + bias ===============
            float pa = ba1, pb = bb1, pa2 = 0.0f, pb2 = 0.0f;
            #pragma unroll
            for (int m = 0; m < 4; ++m){
                pa  = dot2i(iA1i[4*m+0], hp0[m].q[0], pa );
                pb  = dot2i(iB1i[4*m+0], hp0[m].q[0], pb );
                pa2 = dot2i(iA1i[4*m+1], hp0[m].q[1], pa2);
                pb2 = dot2i(iB1i[4*m+1], hp0[m].q[1], pb2);
                pa  = dot2i(iA1i[4*m+2], hp0[m].q[2], pa );
                pb  = dot2i(iB1i[4*m+2], hp0[m].q[2], pb );
                pa2 = dot2i(iA1i[4*m+3], hp0[m].q[3], pa2);
                pb2 = dot2i(iB1i[4*m+3], hp0[m].q[3], pb2);
            }
            const float g1a = (pa + pa2) + (qa + qa2);
            const float g1b = (pb + pb2) + (qb + qb2);

            float act_a1 = __builtin_fmaf(mA, rcp_f(1.0f + exp2_f(g1a * kA)), cA);
            float act_b1 = rcp_f(1.0f + exp2_f(g1b * (-L2E)));
            const float oa1 = xchg32(act_a1, xaddr);
            const float ob1 = xchg32(act_b1, xaddr);
            {
                const float fsel = hi ? ob1 : act_b1;
                const float osel = hi ? act_b1 : ob1;
                c1 = __builtin_fmaf(fsel, c1, act_a1 * oa1);
                const float t1 = __builtin_fmaf(2.0f,
                        rcp_f(1.0f + exp2_f(c1 * (-2.0f * L2E))), -1.0f);
                const float h1 = osel * t1;
                hstore[w][tt][j] = (unsigned short)cvt1(h1);   // per-step slot
            }
            // read h1_new back; next use is next iteration's q-dots (after
            // ~350 cyc of L0 work) -> round trip naturally covered.
            {
                const i4* hv = (const i4*)&hstore[w][tt][0];
                #pragma unroll
                for (int m = 0; m < 4; ++m) hp1[m].v = hv[m];
            }
        }

        // ========= head for the whole chunk: lane t -> y[t] =========
        {
            HP wl4[4], hr[4];
            const i4* wv = (const i4*)&wls[w][0];
            const i4* hv = (const i4*)&hstore[w][lane][0];
            #pragma unroll
            for (int m = 0; m < 4; ++m){ wl4[m].v = wv[m]; hr[m].v = hv[m]; }
            float y = bl, y2 = 0.0f;
            #pragma unroll
            for (int m = 0; m < 4; ++m){
                y  = dot2i(wl4[m].q[0], hr[m].q[0], y );
                y2 = dot2i(wl4[m].q[1], hr[m].q[1], y2);
                y  = dot2i(wl4[m].q[2], hr[m].q[2], y );
                y2 = dot2i(wl4[m].q[3], hr[m].q[3], y2);
            }
            orow[tc * 64 + lane] = y + y2;           // coalesced store
        }
    }
}

extern "C" void kernel_launch(void* const* d_in, const int* in_sizes, int n_in,
                              void* d_out, int out_size, void* d_ws, size_t ws_size,
                              hipStream_t stream) {
    const float* x    = (const float*)d_in[0];
    const float* Wih0 = (const float*)d_in[1];
    const float* Whh0 = (const float*)d_in[2];
    const float* bih0 = (const float*)d_in[3];
    const float* bhh0 = (const float*)d_in[4];
    const float* Wih1 = (const float*)d_in[5];
    const float* Whh1 = (const float*)d_in[6];
    const float* bih1 = (const float*)d_in[7];
    const float* bhh1 = (const float*)d_in[8];
    const float* Wlin = (const float*)d_in[9];
    const float* blin = (const float*)d_in[10];
    float* outp = (float*)d_out;

    dim3 block(256);                 // 4 waves/block, 1 batch row per wave
    dim3 grid(BATCH / 4);            // 512 blocks -> 2048 waves -> 2/SIMD
    hipLaunchKernelGGL(lstm2_v15, grid, block, 0, stream,
                       x, Wih0, Whh0, bih0, bhh0, Wih1, Whh1, bih1, bhh1,
                       Wlin, blin, outp);
}

// Round 16
// 700.960 us; speedup vs baseline: 2.2578x; 1.0064x over previous
//
#include <hip/hip_runtime.h>

// LSTMNet: 2-layer LSTM (in=1, hid=32) + linear(32->1), B=2048, T=1024, fp32.
// R16 = R15 (best family: 792-796us prof) + __attribute__((amdgpu_num_vgpr(128))).
// Theory: the RA keeps choosing a 96-VGPR budget (5 waves/EU tier) although
// only 2 waves/SIMD of work exist; the ~50 overflow live values (h-frags +
// working set atop 96 pinned weights) cycle through AGPRs at ~1-2 copies per
// use -> the persistent ~150 cyc/step gap between measured (761) and modeled
// (~614) issue. waves_per_eu and launch_bounds hints were ignored (R2/R3);
// amdgpu_num_vgpr is the direct lever, untried until now.
// One wave per batch row; 64 lanes = 32 units x 2 halves (i,f | g,o).

typedef int i4 __attribute__((ext_vector_type(4)));

constexpr int BATCH = 2048;
constexpr int TLEN  = 1024;
constexpr int HID   = 32;
constexpr float L2E = 1.44269504088896f;   // log2(e)

#if __has_builtin(__builtin_amdgcn_fdot2_f32_bf16)
typedef __bf16 e2v __attribute__((ext_vector_type(2)));
static __device__ __forceinline__ float dot2i(int a, int b, float c){
    return __builtin_amdgcn_fdot2_f32_bf16(__builtin_bit_cast(e2v, a),
                                           __builtin_bit_cast(e2v, b), c, false);
}
static __device__ __forceinline__ unsigned cvt1(float f){   // RNE to bf16 bits
    unsigned u = __float_as_uint(f);
    return (u + 0x7FFFu + ((u >> 16) & 1u)) >> 16;
}
#else
typedef _Float16 e2v __attribute__((ext_vector_type(2)));
static __device__ __forceinline__ float dot2i(int a, int b, float c){
    return __builtin_amdgcn_fdot2(__builtin_bit_cast(e2v, a),
                                  __builtin_bit_cast(e2v, b), c, false);
}
static __device__ __forceinline__ unsigned cvt1(float f){   // f16 bits
    return (unsigned)__builtin_bit_cast(unsigned short, (_Float16)f);
}
#endif

static __device__ __forceinline__ int pk2(float a, float b){
    return (int)(cvt1(a) | (cvt1(b) << 16));   // low half = a, high half = b
}

union HP { i4 v; int q[4]; };

static __device__ __forceinline__ float rcp_f(float v){ return __builtin_amdgcn_rcpf(v); }
static __device__ __forceinline__ float exp2_f(float v){ return __builtin_amdgcn_exp2f(v); }
static __device__ __forceinline__ float bcastf(float v, int k){
    return __int_as_float(__builtin_amdgcn_readlane(__float_as_int(v), k));
}
static __device__ __forceinline__ float xchg32(float v, int xaddr){
    return __int_as_float(__builtin_amdgcn_ds_bpermute(xaddr, __float_as_int(v)));
}

__global__ void __launch_bounds__(256)
__attribute__((amdgpu_num_vgpr(128)))
lstm2_v16(const float* __restrict__ x,
          const float* __restrict__ Wih0, const float* __restrict__ Whh0,
          const float* __restrict__ bih0, const float* __restrict__ bhh0,
          const float* __restrict__ Wih1, const float* __restrict__ Whh1,
          const float* __restrict__ bih1, const float* __restrict__ bhh1,
          const float* __restrict__ Wlin, const float* __restrict__ blin,
          float* __restrict__ out)
{
    const int tid  = threadIdx.x;
    const int lane = tid & 63;
    const int w    = tid >> 6;                 // wave within block (0..3)
    const int b    = blockIdx.x * 4 + w;       // batch row
    const int j    = lane & 31;
    const int hi   = lane >> 5;                // 0: i,f rows   1: g,o rows
    const int rowA = hi * 64 + j;              // i (hi=0) / g (hi=1)
    const int rowB = rowA + 32;                // f (hi=0) / o (hi=1)
    const int xaddr = (lane ^ 32) << 2;        // bpermute byte addr

    __shared__ alignas(16) unsigned short hb0s[4][32];        // h0 transpose buffer
    __shared__ alignas(16) unsigned short hstore[4][64][40];  // h1 per step, 80B stride
    __shared__ alignas(16) unsigned short wls[4][32];         // packed Wlin copy

    unsigned short* hb0p = &hb0s[w][0];

    // wave-local LDS init (both halves write identical values; no barriers)
    wls[w][j] = (unsigned short)cvt1(Wlin[j]);

    // ---- per-lane weights, packed pairs, PINNED in VGPRs ----
    int wA0i[16], wB0i[16], iA1i[16], iB1i[16], hA1i[16], hB1i[16];
    #pragma unroll
    for (int m = 0; m < 16; ++m){
        wA0i[m] = pk2(Whh0[rowA * HID + 2*m], Whh0[rowA * HID + 2*m + 1]);
        wB0i[m] = pk2(Whh0[rowB * HID + 2*m], Whh0[rowB * HID + 2*m + 1]);
        iA1i[m] = pk2(Wih1[rowA * HID + 2*m], Wih1[rowA * HID + 2*m + 1]);
        iB1i[m] = pk2(Wih1[rowB * HID + 2*m], Wih1[rowB * HID + 2*m + 1]);
        hA1i[m] = pk2(Whh1[rowA * HID + 2*m], Whh1[rowA * HID + 2*m + 1]);
        hB1i[m] = pk2(Whh1[rowB * HID + 2*m], Whh1[rowB * HID + 2*m + 1]);
    }
    #pragma unroll
    for (int m = 0; m < 16; ++m){
        asm volatile("" : "+v"(wA0i[m]), "+v"(wB0i[m]), "+v"(iA1i[m]),
                          "+v"(iB1i[m]), "+v"(hA1i[m]), "+v"(hB1i[m]));
    }

    float wa0 = Wih0[rowA];
    float wb0 = Wih0[rowB];
    float ba0 = bih0[rowA] + bhh0[rowA];
    float bb0 = bih0[rowB] + bhh0[rowB];
    float ba1 = bih1[rowA] + bhh1[rowA];
    float bb1 = bih1[rowB] + bhh1[rowB];
    float bl  = blin[0];
    asm volatile("" : "+v"(wa0), "+v"(wb0), "+v"(ba0), "+v"(bb0),
                      "+v"(ba1), "+v"(bb1), "+v"(bl));

    // act-"a" selector: half0 -> sigmoid, half1 -> tanh (=2*sigm(2x)-1)
    const float kA = hi ? (-2.0f * L2E) : (-L2E);
    const float mA = hi ?  2.0f : 1.0f;
    const float cA = hi ? -1.0f : 0.0f;

    float c0 = 0.0f, c1 = 0.0f;
    HP hp0[4], hp1[4];                         // h0/h1 as packed pairs (regs)
    #pragma unroll
    for (int m = 0; m < 4; ++m){
        hp0[m].v = (i4){0,0,0,0};
        hp1[m].v = (i4){0,0,0,0};
    }

    const float* xrow = x   + (size_t)b * TLEN;
    float*       orow = out + (size_t)b * TLEN;

    for (int tc = 0; tc < TLEN / 64; ++tc){
        const float xchunk = xrow[tc * 64 + lane];   // coalesced, 64 steps

        for (int tt = 0; tt < 64; ++tt){
            const float xt = bcastf(xchunk, tt);

            // ========= layer 0: g = Whh0*h0_prev + Wih0*x + b =========
            float ga  = __builtin_fmaf(wa0, xt, ba0);
            float gb  = __builtin_fmaf(wb0, xt, bb0);
            float ga2 = 0.0f, gb2 = 0.0f;
            #pragma unroll
            for (int m = 0; m < 4; ++m){
                ga  = dot2i(wA0i[4*m+0], hp0[m].q[0], ga );
                gb  = dot2i(wB0i[4*m+0], hp0[m].q[0], gb );
                ga2 = dot2i(wA0i[4*m+1], hp0[m].q[1], ga2);
                gb2 = dot2i(wB0i[4*m+1], hp0[m].q[1], gb2);
                ga  = dot2i(wA0i[4*m+2], hp0[m].q[2], ga );
                gb  = dot2i(wB0i[4*m+2], hp0[m].q[2], gb );
                ga2 = dot2i(wA0i[4*m+3], hp0[m].q[3], ga2);
                gb2 = dot2i(wB0i[4*m+3], hp0[m].q[3], gb2);
            }
            ga += ga2; gb += gb2;

            float act_a = __builtin_fmaf(mA, rcp_f(1.0f + exp2_f(ga * kA)), cA);
            float act_b = rcp_f(1.0f + exp2_f(gb * (-L2E)));
            const float oa = xchg32(act_a, xaddr);
            const float ob = xchg32(act_b, xaddr);
            {
                const float fsel = hi ? ob : act_b;
                const float osel = hi ? act_b : ob;
                c0 = __builtin_fmaf(fsel, c0, act_a * oa);
                const float t0 = __builtin_fmaf(2.0f,
                        rcp_f(1.0f + exp2_f(c0 * (-2.0f * L2E))), -1.0f);
                const float h0 = osel * t0;
                hb0p[j] = (unsigned short)cvt1(h0);  // ds_write_b16 (both halves same)
            }

            // ========= layer 1 part A: q = Whh1*h1_prev (h0-independent) ====
            float qa = 0.0f, qb = 0.0f, qa2 = 0.0f, qb2 = 0.0f;
            #pragma unroll
            for (int m = 0; m < 4; ++m){
                qa  = dot2i(hA1i[4*m+0], hp1[m].q[0], qa );
                qb  = dot2i(hB1i[4*m+0], hp1[m].q[0], qb );
                qa2 = dot2i(hA1i[4*m+1], hp1[m].q[1], qa2);
                qb2 = dot2i(hB1i[4*m+1], hp1[m].q[1], qb2);
                qa  = dot2i(hA1i[4*m+2], hp1[m].q[2], qa );
                qb  = dot2i(hB1i[4*m+2], hp1[m].q[2], qb );
                qa2 = dot2i(hA1i[4*m+3], hp1[m].q[3], qa2);
                qb2 = dot2i(hB1i[4*m+3], hp1[m].q[3], qb2);
            }

            // read h0_new back (latency covered by the q-dots above)
            {
                const i4* hv = (const i4*)hb0p;
                #pragma unroll
                for (int m = 0; m < 4; ++m) hp0[m].v = hv[m];
            }

            // ========= layer 1 part B: p = Wih1*h0_new + bias ===============
            float pa = ba1, pb = bb1, pa2 = 0.0f, pb2 = 0.0f;
            #pragma unroll
            for (int m = 0; m < 4; ++m){
                pa  = dot2i(iA1i[4*m+0], hp0[m].q[0], pa );
                pb  = dot2i(iB1i[4*m+0], hp0[m].q[0], pb );
                pa2 = dot2i(iA1i[4*m+1], hp0[m].q[1], pa2);
                pb2 = dot2i(iB1i[4*m+1], hp0[m].q[1], pb2);
                pa  = dot2i(iA1i[4*m+2], hp0[m].q[2], pa );
                pb  = dot2i(iB1i[4*m+2], hp0[m].q[2], pb );
                pa2 = dot2i(iA1i[4*m+3], hp0[m].q[3], pa2);
                pb2 = dot2i(iB1i[4*m+3], hp0[m].q[3], pb2);
            }
            const float g1a = (pa + pa2) + (qa + qa2);
            const float g1b = (pb + pb2) + (qb + qb2);

            float act_a1 = __builtin_fmaf(mA, rcp_f(1.0f + exp2_f(g1a * kA)), cA);
            float act_b1 = rcp_f(1.0f + exp2_f(g1b * (-L2E)));
            const float oa1 = xchg32(act_a1, xaddr);
            const float ob1 = xchg32(act_b1, xaddr);
            {
                const float fsel = hi ? ob1 : act_b1;
                const float osel = hi ? act_b1 : ob1;
                c1 = __builtin_fmaf(fsel, c1, act_a1 * oa1);
                const float t1 = __builtin_fmaf(2.0f,
                        rcp_f(1.0f + exp2_f(c1 * (-2.0f * L2E))), -1.0f);
                const float h1 = osel * t1;
                hstore[w][tt][j] = (unsigned short)cvt1(h1);   // per-step slot
            }
            // read h1_new back (wave-uniform) for next step's recurrence
            {
                const i4* hv = (const i4*)&hstore[w][tt][0];
                #pragma unroll
                for (int m = 0; m < 4; ++m) hp1[m].v = hv[m];
            }
        }

        // ========= head for the whole chunk: lane t -> y[t] =========
        {
            HP wl4[4], hr[4];
            const i4* wv = (const i4*)&wls[w][0];
            const i4* hv = (const i4*)&hstore[w][lane][0];
            #pragma unroll
            for (int m = 0; m < 4; ++m){ wl4[m].v = wv[m]; hr[m].v = hv[m]; }
            float y = bl, y2 = 0.0f;
            #pragma unroll
            for (int m = 0; m < 4; ++m){
                y  = dot2i(wl4[m].q[0], hr[m].q[0], y );
                y2 = dot2i(wl4[m].q[1], hr[m].q[1], y2);
                y  = dot2i(wl4[m].q[2], hr[m].q[2], y );
                y2 = dot2i(wl4[m].q[3], hr[m].q[3], y2);
            }
            orow[tc * 64 + lane] = y + y2;           // coalesced store
        }
    }
}

extern "C" void kernel_launch(void* const* d_in, const int* in_sizes, int n_in,
                              void* d_out, int out_size, void* d_ws, size_t ws_size,
                              hipStream_t stream) {
    const float* x    = (const float*)d_in[0];
    const float* Wih0 = (const float*)d_in[1];
    const float* Whh0 = (const float*)d_in[2];
    const float* bih0 = (const float*)d_in[3];
    const float* bhh0 = (const float*)d_in[4];
    const float* Wih1 = (const float*)d_in[5];
    const float* Whh1 = (const float*)d_in[6];
    const float* bih1 = (const float*)d_in[7];
    const float* bhh1 = (const float*)d_in[8];
    const float* Wlin = (const float*)d_in[9];
    const float* blin = (const float*)d_in[10];
    float* outp = (float*)d_out;

    dim3 block(256);                 // 4 waves/block, 1 batch row per wave
    dim3 grid(BATCH / 4);            // 512 blocks -> 2048 waves -> 2/SIMD
    hipLaunchKernelGGL(lstm2_v16, grid, block, 0, stream,
                       x, Wih0, Whh0, bih0, bhh0, Wih1, Whh1, bih1, bhh1,
                       Wlin, blin, outp);
}